// Round 1
// baseline (827.497 us; speedup 1.0000x reference)
//
#include <hip/hip_runtime.h>
#include <math.h>

#define B_ROWS 32768
#define D_DIM  256
#define K_CODES 2048

// d_out layout (float elements), reference return order:
// quantized_st [B,D], vq_loss, entropy, encoding_inds [B,1], cluster_metric
#define OUT_Q   0
#define OUT_VQ  8388608
#define OUT_ENT 8388609
#define OUT_IND 8388610
#define OUT_CM  8421378

// ws layout (bytes)
#define WS_SE2   0          // 2048 float
#define WS_SX2   8192       // 32768 float
#define WS_CNT   139264     // 2048 int (memset 0 each launch)
#define WS_DMIN  147456     // 32768 float (selected fp32 dist per row)
#define WS_INDS  278528     // 32768 int
#define WS_MSEP  409600     // 8192 double (per-wave mse partials)
#define WS_DISTP 475136     // 8192 double (per-wave dist partials)

// ---------------------------------------------------------------------------
// Row sum-of-squares for both E (first 2048 rows) and X (next 32768 rows).
// One wave per row; float4 loads; full-wave butterfly.
__global__ __launch_bounds__(256) void k_rowsums(const float* __restrict__ X,
                                                 const float* __restrict__ E,
                                                 float* __restrict__ se2,
                                                 float* __restrict__ sx2) {
  int wave = threadIdx.x >> 6;
  int lane = threadIdx.x & 63;
  int row = blockIdx.x * 4 + wave;
  const float* src = (row < K_CODES) ? (E + (size_t)row * D_DIM)
                                     : (X + (size_t)(row - K_CODES) * D_DIM);
  float4 v = ((const float4*)src)[lane];
  float s = v.x * v.x + v.y * v.y + v.z * v.z + v.w * v.w;
#pragma unroll
  for (int off = 32; off > 0; off >>= 1) s += __shfl_xor(s, off, 64);
  if (lane == 0) {
    if (row < K_CODES) se2[row] = s;
    else               sx2[row - K_CODES] = s;
  }
}

// ---------------------------------------------------------------------------
// Fused fp32 GEMM + argmin. Block: 256 threads, 32 rows x 128 codes.
// Thread (c = tid&31, g = tid>>5) owns rows 4g..4g+3 x codes 4c..4c+3.
// dist is computed with the reference's exact fp32 op order:
//   t = sx + se;  dist = t - 2*dot   (each a single fp32 rounding)
// Tie-break: first (smallest) index on equal fp32 dist, matching np.argmin.
__global__ __launch_bounds__(256) void k_argmin(
    const float* __restrict__ X, const float* __restrict__ E,
    const float* __restrict__ se2, const float* __restrict__ sx2,
    float* __restrict__ out_ind, int* __restrict__ inds,
    float* __restrict__ dmin, int* __restrict__ counts) {
  // E tile transposed [dd][n], stride 132: wave-uniform dd -> lanes read
  // consecutive float4s -> conflict-free; 132*4B keeps 16B alignment.
  __shared__ __align__(16) float Et[32 * 132];
  __shared__ float Xs[32 * 33];  // [r][dd], +1 pad: broadcast reads
  const int tid = threadIdx.x;
  const int c = tid & 31;
  const int g = tid >> 5;
  const int row0 = blockIdx.x * 32;

  float sx[4];
#pragma unroll
  for (int i = 0; i < 4; i++) sx[i] = sx2[row0 + 4 * g + i];

  float runs[4];
  int runk[4];
#pragma unroll
  for (int i = 0; i < 4; i++) { runs[i] = 3.402823466e38f; runk[i] = 0; }

  for (int kt = 0; kt < K_CODES; kt += 128) {
    float acc[4][4];
#pragma unroll
    for (int i = 0; i < 4; i++)
#pragma unroll
      for (int j = 0; j < 4; j++) acc[i][j] = 0.0f;

    for (int dc = 0; dc < D_DIM; dc += 32) {
      __syncthreads();
      // stage E chunk: 128 codes x 32 d, transposed into Et[dd][kk]
#pragma unroll
      for (int rep = 0; rep < 16; rep++) {
        int idx = rep * 256 + tid;
        int kk = idx >> 5, dd = idx & 31;
        Et[dd * 132 + kk] = E[(size_t)(kt + kk) * D_DIM + dc + dd];
      }
      // stage X chunk: 32 rows x 32 d
#pragma unroll
      for (int rep = 0; rep < 4; rep++) {
        int idx = rep * 256 + tid;
        int rr = idx >> 5, dd = idx & 31;
        Xs[rr * 33 + dd] = X[(size_t)(row0 + rr) * D_DIM + dc + dd];
      }
      __syncthreads();
#pragma unroll 4
      for (int dd = 0; dd < 32; dd++) {
        float4 e4 = *(const float4*)&Et[dd * 132 + 4 * c];
#pragma unroll
        for (int i = 0; i < 4; i++) {
          float xv = Xs[(4 * g + i) * 33 + dd];
          acc[i][0] = fmaf(xv, e4.x, acc[i][0]);
          acc[i][1] = fmaf(xv, e4.y, acc[i][1]);
          acc[i][2] = fmaf(xv, e4.z, acc[i][2]);
          acc[i][3] = fmaf(xv, e4.w, acc[i][3]);
        }
      }
    }
    // scores + argmin for this 128-code tile
    float se[4];
#pragma unroll
    for (int j = 0; j < 4; j++) se[j] = se2[kt + 4 * c + j];
#pragma unroll
    for (int i = 0; i < 4; i++) {
      float bs = 3.402823466e38f;
      int bk = 0;
#pragma unroll
      for (int j = 0; j < 4; j++) {
        int k = kt + 4 * c + j;
        float t1 = sx[i] + se[j];          // fp32 round 1 (matches ref)
        float d = t1 - 2.0f * acc[i][j];   // 2*dot exact, fp32 round 2
        if (d < bs) { bs = d; bk = k; }    // ascending j -> first-index ties
      }
      // butterfly over the 32 lanes sharing this row group (bit5 untouched)
#pragma unroll
      for (int off = 1; off < 32; off <<= 1) {
        float os = __shfl_xor(bs, off, 64);
        int ok = __shfl_xor(bk, off, 64);
        if (os < bs || (os == bs && ok < bk)) { bs = os; bk = ok; }
      }
      // cross-tile: strict < keeps the earlier (smaller-k) tile on ties
      if (bs < runs[i]) { runs[i] = bs; runk[i] = bk; }
    }
  }
  if (c == 0) {
#pragma unroll
    for (int i = 0; i < 4; i++) {
      int b = row0 + 4 * g + i;
      out_ind[b] = (float)runk[i];
      inds[b] = runk[i];
      dmin[b] = runs[i];
      atomicAdd(&counts[runk[i]], 1);
    }
  }
}

// ---------------------------------------------------------------------------
// Gather codebook rows, write STE output x + (q - x) (bit-matches reference
// rounding), accumulate per-wave partials: sum (q-x)^2 and sum dist_at_min.
__global__ __launch_bounds__(256) void k_gather(
    const float* __restrict__ X, const float* __restrict__ E,
    const int* __restrict__ inds, const float* __restrict__ dmin,
    float* __restrict__ outq, double* __restrict__ msep,
    double* __restrict__ distp) {
  int wave = threadIdx.x >> 6, lane = threadIdx.x & 63;
  double msum = 0.0;
  double dsum = 0.0;
#pragma unroll
  for (int rr = 0; rr < 4; rr++) {
    int b = blockIdx.x * 16 + wave * 4 + rr;
    int ind = inds[b];
    float4 x4 = ((const float4*)(X + (size_t)b * D_DIM))[lane];
    float4 q4 = ((const float4*)(E + (size_t)ind * D_DIM))[lane];
    float d0 = q4.x - x4.x, d1 = q4.y - x4.y, d2 = q4.z - x4.z, d3 = q4.w - x4.w;
    float4 o;
    o.x = x4.x + d0; o.y = x4.y + d1; o.z = x4.z + d2; o.w = x4.w + d3;
    ((float4*)(outq + (size_t)b * D_DIM))[lane] = o;
    float v = d0 * d0 + d1 * d1 + d2 * d2 + d3 * d3;
#pragma unroll
    for (int off = 32; off > 0; off >>= 1) v += __shfl_xor(v, off, 64);
    if (lane == 0) { msum += (double)v; dsum += (double)dmin[b]; }
  }
  if (lane == 0) {
    int w = blockIdx.x * 4 + wave;
    msep[w] = msum;
    distp[w] = dsum;
  }
}

// ---------------------------------------------------------------------------
// Final scalars: vq_loss = 1.25 * mse, entropy from histogram, cluster metric.
__global__ __launch_bounds__(256) void k_final(
    const int* __restrict__ counts, const double* __restrict__ msep,
    const double* __restrict__ distp, float* __restrict__ out) {
  __shared__ double red[256];
  int t = threadIdx.x;

  double m = 0.0;
  for (int i = t; i < 8192; i += 256) m += msep[i];
  red[t] = m;
  __syncthreads();
  for (int s = 128; s > 0; s >>= 1) {
    if (t < s) red[t] += red[t + s];
    __syncthreads();
  }
  if (t == 0) {
    double mse = red[0] / ((double)B_ROWS * (double)D_DIM);
    // vq_loss = BETA*commitment + embedding = 0.25*mse + mse
    out[OUT_VQ] = (float)(mse * 1.25);
  }
  __syncthreads();

  double d = 0.0;
  for (int i = t; i < 8192; i += 256) d += distp[i];
  red[t] = d;
  __syncthreads();
  for (int s = 128; s > 0; s >>= 1) {
    if (t < s) red[t] += red[t + s];
    __syncthreads();
  }
  if (t == 0) out[OUT_CM] = (float)(red[0] / (double)B_ROWS);
  __syncthreads();

  double e = 0.0;
  for (int k = t; k < K_CODES; k += 256) {
    float p = (float)counts[k] * (1.0f / 32768.0f);  // exact (pow2 divide)
    e += (double)(p * logf(p + 1e-10f));
  }
  red[t] = e;
  __syncthreads();
  for (int s = 128; s > 0; s >>= 1) {
    if (t < s) red[t] += red[t + s];
    __syncthreads();
  }
  if (t == 0) out[OUT_ENT] = (float)(-red[0]);
}

// ---------------------------------------------------------------------------
extern "C" void kernel_launch(void* const* d_in, const int* in_sizes, int n_in,
                              void* d_out, int out_size, void* d_ws,
                              size_t ws_size, hipStream_t stream) {
  const float* X = (const float*)d_in[0];  // latents [32768,256]
  const float* E = (const float*)d_in[1];  // embedding [2048,256]
  float* out = (float*)d_out;
  char* ws = (char*)d_ws;
  float* se2 = (float*)(ws + WS_SE2);
  float* sx2 = (float*)(ws + WS_SX2);
  int* counts = (int*)(ws + WS_CNT);
  float* dmin = (float*)(ws + WS_DMIN);
  int* inds = (int*)(ws + WS_INDS);
  double* msep = (double*)(ws + WS_MSEP);
  double* distp = (double*)(ws + WS_DISTP);

  hipMemsetAsync(counts, 0, K_CODES * sizeof(int), stream);
  k_rowsums<<<(K_CODES + B_ROWS) / 4, 256, 0, stream>>>(X, E, se2, sx2);
  k_argmin<<<B_ROWS / 32, 256, 0, stream>>>(X, E, se2, sx2, out + OUT_IND,
                                            inds, dmin, counts);
  k_gather<<<B_ROWS / 16, 256, 0, stream>>>(X, E, inds, dmin, out + OUT_Q,
                                            msep, distp);
  k_final<<<1, 256, 0, stream>>>(counts, msep, distp, out);
}

// Round 2
// 532.673 us; speedup vs baseline: 1.5535x; 1.5535x over previous
//
#include <hip/hip_runtime.h>
#include <math.h>

#define B_ROWS 32768
#define D_DIM  256
#define K_CODES 2048

// d_out layout (float elements), reference return order:
// quantized_st [B,D], vq_loss, entropy, encoding_inds [B,1], cluster_metric
#define OUT_Q   0
#define OUT_VQ  8388608
#define OUT_ENT 8388609
#define OUT_IND 8388610
#define OUT_CM  8421378

// Per-tile argmin candidates live in the d_out Q region (overwritten later by
// k_gather): cs = out[0 .. 16*32768), ck = out[16*32768 .. 32*32768) as ints.
#define CAND_S  0
#define CAND_K  524288

// ws layout (bytes)
#define WS_SE2   0          // 2048 float
#define WS_SX2   8192       // 32768 float
#define WS_CNT   139264     // 2048 int (memset 0 each launch)
#define WS_DMIN  147456     // 32768 float (selected fp32 dist per row)
#define WS_INDS  278528     // 32768 int
#define WS_MSEP  409600     // 8192 double (per-wave mse partials)
#define WS_DISTP 475136     // 8192 double (per-wave dist partials)

// ---------------------------------------------------------------------------
// Row sum-of-squares for both E (first 2048 rows) and X (next 32768 rows).
__global__ __launch_bounds__(256) void k_rowsums(const float* __restrict__ X,
                                                 const float* __restrict__ E,
                                                 float* __restrict__ se2,
                                                 float* __restrict__ sx2) {
  int wave = threadIdx.x >> 6;
  int lane = threadIdx.x & 63;
  int row = blockIdx.x * 4 + wave;
  const float* src = (row < K_CODES) ? (E + (size_t)row * D_DIM)
                                     : (X + (size_t)(row - K_CODES) * D_DIM);
  float4 v = ((const float4*)src)[lane];
  float s = v.x * v.x + v.y * v.y + v.z * v.z + v.w * v.w;
#pragma unroll
  for (int off = 32; off > 0; off >>= 1) s += __shfl_xor(s, off, 64);
  if (lane == 0) {
    if (row < K_CODES) se2[row] = s;
    else               sx2[row - K_CODES] = s;
  }
}

// ---------------------------------------------------------------------------
// Fused fp32 GEMM + per-tile argmin. Block: 256 threads = 16 c-lanes x 16
// g-groups; block tile = 128 rows x 512 codes (one K quarter, 4 kt-tiles of
// 128). Thread tile = 8 rows x 8 codes -> 64 FMAs per 4 LDS b128 reads.
// Both X and E chunks staged transposed [dd][row/code], stride 132:
//   - compute reads are dense consecutive-float4 (conflict-free) or broadcast
//   - transpose staging writes are 4-way conflicted (bank = (16dq+4u+kk)%32)
// dist formula / accumulation order bit-identical to the round-1 kernel
// (absmax 0.0): single fp32 FMA chain over d ascending; d = (sx+se) - 2*dot.
__global__ __launch_bounds__(256, 4) void k_argmin(
    const float* __restrict__ X, const float* __restrict__ E,
    const float* __restrict__ se2, const float* __restrict__ sx2,
    float* __restrict__ cs, int* __restrict__ ck) {
  __shared__ __align__(16) float Et[32 * 132];
  __shared__ __align__(16) float Xt[32 * 132];
  const int tid = threadIdx.x;
  const int c = tid & 15;
  const int g = tid >> 4;
  const int rowblk = blockIdx.x >> 2;
  const int q = blockIdx.x & 3;
  const int row0 = rowblk * 128;
  const int code0 = q * 512;
  const int r8 = tid >> 3;  // 0..31 (staging row index base)
  const int dq = tid & 7;   // 0..7  (staging float4 column)

  for (int kt = 0; kt < 4; kt++) {
    const int kbase = code0 + kt * 128;
    float acc[8][8];
#pragma unroll
    for (int i = 0; i < 8; i++)
#pragma unroll
      for (int j = 0; j < 8; j++) acc[i][j] = 0.0f;

    for (int dc = 0; dc < D_DIM; dc += 32) {
      __syncthreads();
      // stage E tile (128 codes x 32 dd) and X tile (128 rows x 32 dd),
      // both transposed to [dd][*]; float4 global loads, b32 LDS writes.
#pragma unroll
      for (int rep = 0; rep < 4; rep++) {
        int kk = rep * 32 + r8;
        float4 ev = *(const float4*)&E[(size_t)(kbase + kk) * D_DIM + dc + 4 * dq];
        Et[(4 * dq + 0) * 132 + kk] = ev.x;
        Et[(4 * dq + 1) * 132 + kk] = ev.y;
        Et[(4 * dq + 2) * 132 + kk] = ev.z;
        Et[(4 * dq + 3) * 132 + kk] = ev.w;
        float4 xv = *(const float4*)&X[(size_t)(row0 + kk) * D_DIM + dc + 4 * dq];
        Xt[(4 * dq + 0) * 132 + kk] = xv.x;
        Xt[(4 * dq + 1) * 132 + kk] = xv.y;
        Xt[(4 * dq + 2) * 132 + kk] = xv.z;
        Xt[(4 * dq + 3) * 132 + kk] = xv.w;
      }
      __syncthreads();
#pragma unroll 4
      for (int dd = 0; dd < 32; dd++) {
        float4 x0 = *(const float4*)&Xt[dd * 132 + 8 * g];
        float4 x1 = *(const float4*)&Xt[dd * 132 + 8 * g + 4];
        float4 e0 = *(const float4*)&Et[dd * 132 + 4 * c];
        float4 e1 = *(const float4*)&Et[dd * 132 + 4 * c + 64];
        float xr[8] = {x0.x, x0.y, x0.z, x0.w, x1.x, x1.y, x1.z, x1.w};
        float er[8] = {e0.x, e0.y, e0.z, e0.w, e1.x, e1.y, e1.z, e1.w};
#pragma unroll
        for (int i = 0; i < 8; i++)
#pragma unroll
          for (int j = 0; j < 8; j++)
            acc[i][j] = fmaf(xr[i], er[j], acc[i][j]);
      }
    }
    // epilogue: scores + per-tile argmin (first-index ties at every level)
    float se[8];
#pragma unroll
    for (int t = 0; t < 2; t++)
#pragma unroll
      for (int j = 0; j < 4; j++) se[t * 4 + j] = se2[kbase + 64 * t + 4 * c + j];
#pragma unroll
    for (int i = 0; i < 8; i++) {
      float sx = sx2[row0 + 8 * g + i];
      float bs = 3.402823466e38f;
      int bk = 0;
#pragma unroll
      for (int t = 0; t < 2; t++)
#pragma unroll
        for (int j = 0; j < 4; j++) {
          int k = kbase + 64 * t + 4 * c + j;
          float t1 = sx + se[t * 4 + j];             // fp32 round 1 (matches ref)
          float d = t1 - 2.0f * acc[i][t * 4 + j];   // 2*dot exact, round 2
          if (d < bs) { bs = d; bk = k; }            // ascending k -> first-index
        }
      // butterfly over the 16 c-lanes (tid bits 0..3; g bits untouched)
#pragma unroll
      for (int off = 1; off < 16; off <<= 1) {
        float os = __shfl_xor(bs, off, 64);
        int ok = __shfl_xor(bk, off, 64);
        if (os < bs || (os == bs && ok < bk)) { bs = os; bk = ok; }
      }
      if (c == 0) {
        int row = row0 + 8 * g + i;
        int t16 = q * 4 + kt;  // tiles ascending in k
        cs[t16 * B_ROWS + row] = bs;
        ck[t16 * B_ROWS + row] = bk;
      }
    }
  }
}

// ---------------------------------------------------------------------------
// Merge 16 per-tile candidates per row (tiles ascending in k; strict < keeps
// the smaller-k tile on ties), emit inds/dmin/hist.
__global__ __launch_bounds__(256) void k_merge(
    const float* __restrict__ cs, const int* __restrict__ ck,
    float* __restrict__ out_ind, int* __restrict__ inds,
    float* __restrict__ dmin, int* __restrict__ counts) {
  int r = blockIdx.x * 256 + threadIdx.x;
  float bs = cs[r];
  int bk = ck[r];
#pragma unroll
  for (int t = 1; t < 16; t++) {
    float s = cs[t * B_ROWS + r];
    int k = ck[t * B_ROWS + r];
    if (s < bs) { bs = s; bk = k; }
  }
  out_ind[r] = (float)bk;
  inds[r] = bk;
  dmin[r] = bs;
  atomicAdd(&counts[bk], 1);
}

// ---------------------------------------------------------------------------
// Gather codebook rows, write STE output x + (q - x), per-wave partials.
__global__ __launch_bounds__(256) void k_gather(
    const float* __restrict__ X, const float* __restrict__ E,
    const int* __restrict__ inds, const float* __restrict__ dmin,
    float* __restrict__ outq, double* __restrict__ msep,
    double* __restrict__ distp) {
  int wave = threadIdx.x >> 6, lane = threadIdx.x & 63;
  double msum = 0.0;
  double dsum = 0.0;
#pragma unroll
  for (int rr = 0; rr < 4; rr++) {
    int b = blockIdx.x * 16 + wave * 4 + rr;
    int ind = inds[b];
    float4 x4 = ((const float4*)(X + (size_t)b * D_DIM))[lane];
    float4 q4 = ((const float4*)(E + (size_t)ind * D_DIM))[lane];
    float d0 = q4.x - x4.x, d1 = q4.y - x4.y, d2 = q4.z - x4.z, d3 = q4.w - x4.w;
    float4 o;
    o.x = x4.x + d0; o.y = x4.y + d1; o.z = x4.z + d2; o.w = x4.w + d3;
    ((float4*)(outq + (size_t)b * D_DIM))[lane] = o;
    float v = d0 * d0 + d1 * d1 + d2 * d2 + d3 * d3;
#pragma unroll
    for (int off = 32; off > 0; off >>= 1) v += __shfl_xor(v, off, 64);
    if (lane == 0) { msum += (double)v; dsum += (double)dmin[b]; }
  }
  if (lane == 0) {
    int w = blockIdx.x * 4 + wave;
    msep[w] = msum;
    distp[w] = dsum;
  }
}

// ---------------------------------------------------------------------------
// Final scalars: vq_loss = 1.25 * mse, entropy from histogram, cluster metric.
__global__ __launch_bounds__(256) void k_final(
    const int* __restrict__ counts, const double* __restrict__ msep,
    const double* __restrict__ distp, float* __restrict__ out) {
  __shared__ double red[256];
  int t = threadIdx.x;

  double m = 0.0;
  for (int i = t; i < 8192; i += 256) m += msep[i];
  red[t] = m;
  __syncthreads();
  for (int s = 128; s > 0; s >>= 1) {
    if (t < s) red[t] += red[t + s];
    __syncthreads();
  }
  if (t == 0) {
    double mse = red[0] / ((double)B_ROWS * (double)D_DIM);
    out[OUT_VQ] = (float)(mse * 1.25);  // 0.25*commit + embed = 1.25*mse
  }
  __syncthreads();

  double d = 0.0;
  for (int i = t; i < 8192; i += 256) d += distp[i];
  red[t] = d;
  __syncthreads();
  for (int s = 128; s > 0; s >>= 1) {
    if (t < s) red[t] += red[t + s];
    __syncthreads();
  }
  if (t == 0) out[OUT_CM] = (float)(red[0] / (double)B_ROWS);
  __syncthreads();

  double e = 0.0;
  for (int k = t; k < K_CODES; k += 256) {
    float p = (float)counts[k] * (1.0f / 32768.0f);  // exact (pow2 divide)
    e += (double)(p * logf(p + 1e-10f));
  }
  red[t] = e;
  __syncthreads();
  for (int s = 128; s > 0; s >>= 1) {
    if (t < s) red[t] += red[t + s];
    __syncthreads();
  }
  if (t == 0) out[OUT_ENT] = (float)(-red[0]);
}

// ---------------------------------------------------------------------------
extern "C" void kernel_launch(void* const* d_in, const int* in_sizes, int n_in,
                              void* d_out, int out_size, void* d_ws,
                              size_t ws_size, hipStream_t stream) {
  const float* X = (const float*)d_in[0];  // latents [32768,256]
  const float* E = (const float*)d_in[1];  // embedding [2048,256]
  float* out = (float*)d_out;
  char* ws = (char*)d_ws;
  float* se2 = (float*)(ws + WS_SE2);
  float* sx2 = (float*)(ws + WS_SX2);
  int* counts = (int*)(ws + WS_CNT);
  float* dmin = (float*)(ws + WS_DMIN);
  int* inds = (int*)(ws + WS_INDS);
  double* msep = (double*)(ws + WS_MSEP);
  double* distp = (double*)(ws + WS_DISTP);
  float* cs = out + CAND_S;        // scratch in d_out Q region
  int* ckp = (int*)(out + CAND_K); // overwritten by k_gather afterwards

  hipMemsetAsync(counts, 0, K_CODES * sizeof(int), stream);
  k_rowsums<<<(K_CODES + B_ROWS) / 4, 256, 0, stream>>>(X, E, se2, sx2);
  k_argmin<<<1024, 256, 0, stream>>>(X, E, se2, sx2, cs, ckp);
  k_merge<<<B_ROWS / 256, 256, 0, stream>>>(cs, ckp, out + OUT_IND, inds, dmin,
                                            counts);
  k_gather<<<B_ROWS / 16, 256, 0, stream>>>(X, E, inds, dmin, out + OUT_Q,
                                            msep, distp);
  k_final<<<1, 256, 0, stream>>>(counts, msep, distp, out);
}

// Round 3
// 279.621 us; speedup vs baseline: 2.9594x; 1.9050x over previous
//
#include <hip/hip_runtime.h>
#include <math.h>

#define B_ROWS 32768
#define D_DIM  256
#define K_CODES 2048

// d_out layout (float elements), reference return order:
// quantized_st [B,D], vq_loss, entropy, encoding_inds [B,1], cluster_metric
#define OUT_Q   0
#define OUT_VQ  8388608
#define OUT_ENT 8388609
#define OUT_IND 8388610
#define OUT_CM  8421378

// A_cat [32768][512] fp16 = 33.55 MB lives in the d_out Q region (exact fit);
// k_gather overwrites it with the real output afterwards.

// ws layout (bytes)
#define WS_SE2   0          // 2048 float
#define WS_SX2   8192       // 32768 float
#define WS_CNT   139264     // 2048 int (memset 0 each launch)
#define WS_DMIN  147456     // 32768 float
#define WS_INDS  278528     // 32768 int
#define WS_MSEP  409600     // 8192 double
#define WS_DISTP 475136     // 8192 double
#define WS_BCAT  540672     // 2048 x 768 fp16 = 3 MB
#define WS_CS    3686400    // 16 x 32768 float (per-tile cand scores)
#define WS_CK    5783552    // 16 x 32768 int   (per-tile cand indices)

typedef _Float16 f16x8 __attribute__((ext_vector_type(8)));
typedef float f32x4 __attribute__((ext_vector_type(4)));
typedef union { _Float16 h[4]; uint2 u2; } h4pack;

// ---------------------------------------------------------------------------
// X -> fp16 split A_cat[row][0:256]=hi=fp16(x), [256:512]=fp16((x-hi)*2^12);
// also sx2 (bit-identical math to the verified round-2 rowsums).
__global__ __launch_bounds__(256) void k_convA(const float* __restrict__ X,
                                               _Float16* __restrict__ A,
                                               float* __restrict__ sx2) {
  int w = threadIdx.x >> 6, lane = threadIdx.x & 63;
  int row = blockIdx.x * 4 + w;
  float4 v = ((const float4*)(X + (size_t)row * D_DIM))[lane];
  float s = v.x * v.x + v.y * v.y + v.z * v.z + v.w * v.w;
#pragma unroll
  for (int off = 32; off > 0; off >>= 1) s += __shfl_xor(s, off, 64);
  if (lane == 0) sx2[row] = s;
  h4pack hi, lo;
  hi.h[0] = (_Float16)v.x; hi.h[1] = (_Float16)v.y;
  hi.h[2] = (_Float16)v.z; hi.h[3] = (_Float16)v.w;
  lo.h[0] = (_Float16)((v.x - (float)hi.h[0]) * 4096.0f);
  lo.h[1] = (_Float16)((v.y - (float)hi.h[1]) * 4096.0f);
  lo.h[2] = (_Float16)((v.z - (float)hi.h[2]) * 4096.0f);
  lo.h[3] = (_Float16)((v.w - (float)hi.h[3]) * 4096.0f);
  *(uint2*)&A[(size_t)row * 512 + 4 * lane] = hi.u2;
  *(uint2*)&A[(size_t)row * 512 + 256 + 4 * lane] = lo.u2;
}

// ---------------------------------------------------------------------------
// E -> B_cat[k][0:256]=B1=fp16(e*2^22), [256:512]=B1*2^-12 (exact shift),
// [512:768]=B3=fp16(e*2^22 - B1); also se2 (bit-identical to round-2).
// GEMM terms: hi*B1 + (lo*2^12)*B2 + hi*B3 = x * (e*2^22); all pow2 exact.
__global__ __launch_bounds__(256) void k_convB(const float* __restrict__ E,
                                               _Float16* __restrict__ Bc,
                                               float* __restrict__ se2) {
  int w = threadIdx.x >> 6, lane = threadIdx.x & 63;
  int row = blockIdx.x * 4 + w;
  float4 v = ((const float4*)(E + (size_t)row * D_DIM))[lane];
  float s = v.x * v.x + v.y * v.y + v.z * v.z + v.w * v.w;
#pragma unroll
  for (int off = 32; off > 0; off >>= 1) s += __shfl_xor(s, off, 64);
  if (lane == 0) se2[row] = s;
  const float S = 4194304.0f;      // 2^22
  const float SH = 0.000244140625f; // 2^-12
  float e0 = v.x * S, e1 = v.y * S, e2 = v.z * S, e3 = v.w * S;
  h4pack b1, b2, b3;
  b1.h[0] = (_Float16)e0; b1.h[1] = (_Float16)e1;
  b1.h[2] = (_Float16)e2; b1.h[3] = (_Float16)e3;
  b2.h[0] = (_Float16)((float)b1.h[0] * SH);
  b2.h[1] = (_Float16)((float)b1.h[1] * SH);
  b2.h[2] = (_Float16)((float)b1.h[2] * SH);
  b2.h[3] = (_Float16)((float)b1.h[3] * SH);
  b3.h[0] = (_Float16)(e0 - (float)b1.h[0]);
  b3.h[1] = (_Float16)(e1 - (float)b1.h[1]);
  b3.h[2] = (_Float16)(e2 - (float)b1.h[2]);
  b3.h[3] = (_Float16)(e3 - (float)b1.h[3]);
  *(uint2*)&Bc[(size_t)row * 768 + 4 * lane] = b1.u2;
  *(uint2*)&Bc[(size_t)row * 768 + 256 + 4 * lane] = b2.u2;
  *(uint2*)&Bc[(size_t)row * 768 + 512 + 4 * lane] = b3.u2;
}

// ---------------------------------------------------------------------------
// MFMA GEMM (M=32768, N=2048, K_eff=768 fp16) + fused per-block argmin.
// Block 256 thr = 4 waves (2x2 over a 128x128 tile); BK=32; m97 structure:
// global_load_lds width-16 staging, 8 ds_read_b128 + 16 MFMA per wave/K-step.
// acc = dot * 2^22; epilogue d = (sx+se) - acc*2^-21 (exact pow2 mul, one
// rounded subtract -> same rounding sequence as the fp32 reference).
__global__ __launch_bounds__(256, 3) void k_mfma(
    const _Float16* __restrict__ A, const _Float16* __restrict__ Bc,
    const float* __restrict__ se2, const float* __restrict__ sx2,
    float* __restrict__ cs, int* __restrict__ ck) {
  __shared__ _Float16 As[128 * 32];  // [row][k] row-major, 64 B rows, no pad
  __shared__ _Float16 Bs[128 * 32];  // [code][k]
  __shared__ float sxs[128], ses[128];
  __shared__ float sred[2][128];
  __shared__ int ired[2][128];
  const int tid = threadIdx.x;
  const int w = tid >> 6, lane = tid & 63;
  const int rowblk = blockIdx.x >> 4, colblk = blockIdx.x & 15;
  const int row0 = rowblk * 128, col0 = colblk * 128;
  const int lr = lane >> 2, lc = lane & 3;  // staging: row-in-slice, 16B col
  const int q = lane >> 4, c = lane & 15;   // MFMA lane decomposition
  const int wr = (w >> 1) * 64, wc = (w & 1) * 64;

  if (tid < 128) { sxs[tid] = sx2[row0 + tid]; ses[tid] = se2[col0 + tid]; }

  f32x4 acc[4][4];
#pragma unroll
  for (int i = 0; i < 4; i++)
#pragma unroll
    for (int j = 0; j < 4; j++) acc[i][j] = (f32x4){0.f, 0.f, 0.f, 0.f};

  for (int kt = 0; kt < 24; ++kt) {
    // A col remap: s0 -> hi, s1 -> lo (bytes 512..1023), s2 -> hi again
    int a_off = (kt < 8) ? kt * 64 : (kt < 16) ? 512 + (kt - 8) * 64
                                               : (kt - 16) * 64;
    int b_off = kt * 64;
    __syncthreads();  // previous iter's frag reads done before overwrite
#pragma unroll
    for (int t = 0; t < 2; ++t) {
      int s = w * 2 + t;  // 8 slices of 16 rows each, for A and for B
      const char* ga = (const char*)A +
          (((size_t)(row0 + s * 16 + lr)) << 10) + a_off + lc * 16;
      const char* gb = (const char*)Bc +
          ((size_t)(col0 + s * 16 + lr)) * 1536 + b_off + lc * 16;
      __builtin_amdgcn_global_load_lds(
          (const __attribute__((address_space(1))) unsigned int*)ga,
          (__attribute__((address_space(3))) unsigned int*)((char*)As + s * 1024),
          16, 0, 0);
      __builtin_amdgcn_global_load_lds(
          (const __attribute__((address_space(1))) unsigned int*)gb,
          (__attribute__((address_space(3))) unsigned int*)((char*)Bs + s * 1024),
          16, 0, 0);
    }
    __builtin_amdgcn_s_waitcnt(0x0f70);  // vmcnt(0)
    __syncthreads();
    f16x8 af[4], bf[4];
#pragma unroll
    for (int i = 0; i < 4; ++i) {
      af[i] = *(const f16x8*)&As[(wr + i * 16 + c) * 32 + q * 8];
      bf[i] = *(const f16x8*)&Bs[(wc + i * 16 + c) * 32 + q * 8];
    }
#pragma unroll
    for (int i = 0; i < 4; ++i)
#pragma unroll
      for (int j = 0; j < 4; ++j)
        acc[i][j] =
            __builtin_amdgcn_mfma_f32_16x16x32_f16(af[i], bf[j], acc[i][j], 0, 0, 0);
  }

  // ---- fused argmin epilogue (C layout: col=lane&15, row=q*4+reg) ----
  const float inv = 4.76837158203125e-07f;  // 2^-21, exact pow2
#pragma unroll
  for (int i = 0; i < 4; ++i) {
#pragma unroll
    for (int r = 0; r < 4; ++r) {
      int lrow = wr + i * 16 + q * 4 + r;
      float sx = sxs[lrow];
      float bs = 3.402823466e38f;
      int bk = 0;
#pragma unroll
      for (int j = 0; j < 4; ++j) {  // ascending j -> ascending code
        int nloc = wc + j * 16 + c;
        float t1 = sx + ses[nloc];          // fp32 round 1 (matches ref)
        float d = t1 - acc[i][j][r] * inv;  // exact mul, fp32 round 2
        if (d < bs) { bs = d; bk = col0 + nloc; }
      }
#pragma unroll
      for (int off = 1; off < 16; off <<= 1) {  // reduce over c, q preserved
        float os = __shfl_xor(bs, off, 64);
        int ok = __shfl_xor(bk, off, 64);
        if (os < bs || (os == bs && ok < bk)) { bs = os; bk = ok; }
      }
      if (c == 0) { sred[w & 1][lrow] = bs; ired[w & 1][lrow] = bk; }
    }
  }
  __syncthreads();
  if (tid < 128) {
    float s0 = sred[0][tid]; int k0 = ired[0][tid];
    float s1 = sred[1][tid]; int k1 = ired[1][tid];
    if (s1 < s0) { s0 = s1; k0 = k1; }  // half 0 = lower codes: strict <
    cs[colblk * B_ROWS + row0 + tid] = s0;
    ck[colblk * B_ROWS + row0 + tid] = k0;
  }
}

// ---------------------------------------------------------------------------
// Merge 16 per-tile candidates per row (tiles ascending in k).
__global__ __launch_bounds__(256) void k_merge(
    const float* __restrict__ cs, const int* __restrict__ ck,
    float* __restrict__ out_ind, int* __restrict__ inds,
    float* __restrict__ dmin, int* __restrict__ counts) {
  int r = blockIdx.x * 256 + threadIdx.x;
  float bs = cs[r];
  int bk = ck[r];
#pragma unroll
  for (int t = 1; t < 16; t++) {
    float s = cs[t * B_ROWS + r];
    int k = ck[t * B_ROWS + r];
    if (s < bs) { bs = s; bk = k; }
  }
  out_ind[r] = (float)bk;
  inds[r] = bk;
  dmin[r] = bs;
  atomicAdd(&counts[bk], 1);
}

// ---------------------------------------------------------------------------
// Gather codebook rows (from ORIGINAL fp32 E), STE output, per-wave partials.
__global__ __launch_bounds__(256) void k_gather(
    const float* __restrict__ X, const float* __restrict__ E,
    const int* __restrict__ inds, const float* __restrict__ dmin,
    float* __restrict__ outq, double* __restrict__ msep,
    double* __restrict__ distp) {
  int wave = threadIdx.x >> 6, lane = threadIdx.x & 63;
  double msum = 0.0;
  double dsum = 0.0;
#pragma unroll
  for (int rr = 0; rr < 4; rr++) {
    int b = blockIdx.x * 16 + wave * 4 + rr;
    int ind = inds[b];
    float4 x4 = ((const float4*)(X + (size_t)b * D_DIM))[lane];
    float4 q4 = ((const float4*)(E + (size_t)ind * D_DIM))[lane];
    float d0 = q4.x - x4.x, d1 = q4.y - x4.y, d2 = q4.z - x4.z, d3 = q4.w - x4.w;
    float4 o;
    o.x = x4.x + d0; o.y = x4.y + d1; o.z = x4.z + d2; o.w = x4.w + d3;
    ((float4*)(outq + (size_t)b * D_DIM))[lane] = o;
    float v = d0 * d0 + d1 * d1 + d2 * d2 + d3 * d3;
#pragma unroll
    for (int off = 32; off > 0; off >>= 1) v += __shfl_xor(v, off, 64);
    if (lane == 0) { msum += (double)v; dsum += (double)dmin[b]; }
  }
  if (lane == 0) {
    int w = blockIdx.x * 4 + wave;
    msep[w] = msum;
    distp[w] = dsum;
  }
}

// ---------------------------------------------------------------------------
__global__ __launch_bounds__(256) void k_final(
    const int* __restrict__ counts, const double* __restrict__ msep,
    const double* __restrict__ distp, float* __restrict__ out) {
  __shared__ double red[256];
  int t = threadIdx.x;

  double m = 0.0;
  for (int i = t; i < 8192; i += 256) m += msep[i];
  red[t] = m;
  __syncthreads();
  for (int s = 128; s > 0; s >>= 1) {
    if (t < s) red[t] += red[t + s];
    __syncthreads();
  }
  if (t == 0) {
    double mse = red[0] / ((double)B_ROWS * (double)D_DIM);
    out[OUT_VQ] = (float)(mse * 1.25);  // 0.25*commit + embed
  }
  __syncthreads();

  double d = 0.0;
  for (int i = t; i < 8192; i += 256) d += distp[i];
  red[t] = d;
  __syncthreads();
  for (int s = 128; s > 0; s >>= 1) {
    if (t < s) red[t] += red[t + s];
    __syncthreads();
  }
  if (t == 0) out[OUT_CM] = (float)(red[0] / (double)B_ROWS);
  __syncthreads();

  double e = 0.0;
  for (int k = t; k < K_CODES; k += 256) {
    float p = (float)counts[k] * (1.0f / 32768.0f);
    e += (double)(p * logf(p + 1e-10f));
  }
  red[t] = e;
  __syncthreads();
  for (int s = 128; s > 0; s >>= 1) {
    if (t < s) red[t] += red[t + s];
    __syncthreads();
  }
  if (t == 0) out[OUT_ENT] = (float)(-red[0]);
}

// ---------------------------------------------------------------------------
extern "C" void kernel_launch(void* const* d_in, const int* in_sizes, int n_in,
                              void* d_out, int out_size, void* d_ws,
                              size_t ws_size, hipStream_t stream) {
  const float* X = (const float*)d_in[0];  // latents [32768,256]
  const float* E = (const float*)d_in[1];  // embedding [2048,256]
  float* out = (float*)d_out;
  char* ws = (char*)d_ws;
  float* se2 = (float*)(ws + WS_SE2);
  float* sx2 = (float*)(ws + WS_SX2);
  int* counts = (int*)(ws + WS_CNT);
  float* dmin = (float*)(ws + WS_DMIN);
  int* inds = (int*)(ws + WS_INDS);
  double* msep = (double*)(ws + WS_MSEP);
  double* distp = (double*)(ws + WS_DISTP);
  _Float16* Bcat = (_Float16*)(ws + WS_BCAT);
  float* cs = (float*)(ws + WS_CS);
  int* ckp = (int*)(ws + WS_CK);
  _Float16* Acat = (_Float16*)d_out;  // Q region; k_gather overwrites later

  hipMemsetAsync(counts, 0, K_CODES * sizeof(int), stream);
  k_convA<<<B_ROWS / 4, 256, 0, stream>>>(X, Acat, sx2);
  k_convB<<<K_CODES / 4, 256, 0, stream>>>(E, Bcat, se2);
  k_mfma<<<(B_ROWS / 128) * (K_CODES / 128), 256, 0, stream>>>(
      Acat, Bcat, se2, sx2, cs, ckp);
  k_merge<<<B_ROWS / 256, 256, 0, stream>>>(cs, ckp, out + OUT_IND, inds, dmin,
                                            counts);
  k_gather<<<B_ROWS / 16, 256, 0, stream>>>(X, E, inds, dmin, out + OUT_Q,
                                            msep, distp);
  k_final<<<1, 256, 0, stream>>>(counts, msep, distp, out);
}

// Round 4
// 277.028 us; speedup vs baseline: 2.9871x; 1.0094x over previous
//
#include <hip/hip_runtime.h>
#include <math.h>

#define B_ROWS 32768
#define D_DIM  256
#define K_CODES 2048

// d_out layout (float elements), reference return order:
// quantized_st [B,D], vq_loss, entropy, encoding_inds [B,1], cluster_metric
#define OUT_Q   0
#define OUT_VQ  8388608
#define OUT_ENT 8388609
#define OUT_IND 8388610
#define OUT_CM  8421378

// A_cat [32768][512] fp16 = 33.55 MB lives in the d_out Q region (exact fit);
// k_gather overwrites it with the real output afterwards.

// ws layout (bytes)
#define WS_SE2   0          // 2048 float
#define WS_SX2   8192       // 32768 float
#define WS_CNT   139264     // 2048 int   (memset 0 each launch)
#define WS_PACK  147456     // 32768 u64  (memset 0xFF each launch)
#define WS_MSEP  409600     // 8192 double
#define WS_DISTP 475136     // 8192 double
#define WS_BCAT  540672     // 2048 x 768 fp16 = 3 MB

typedef _Float16 f16x8 __attribute__((ext_vector_type(8)));
typedef float f32x4 __attribute__((ext_vector_type(4)));
typedef union { _Float16 h[4]; uint2 u2; } h4pack;

// ---------------------------------------------------------------------------
// X -> fp16 split A_cat[row][0:256]=hi=fp16(x), [256:512]=fp16((x-hi)*2^12);
// also sx2. (Bit-identical to the verified round-3 kernel.)
__global__ __launch_bounds__(256) void k_convA(const float* __restrict__ X,
                                               _Float16* __restrict__ A,
                                               float* __restrict__ sx2) {
  int w = threadIdx.x >> 6, lane = threadIdx.x & 63;
  int row = blockIdx.x * 4 + w;
  float4 v = ((const float4*)(X + (size_t)row * D_DIM))[lane];
  float s = v.x * v.x + v.y * v.y + v.z * v.z + v.w * v.w;
#pragma unroll
  for (int off = 32; off > 0; off >>= 1) s += __shfl_xor(s, off, 64);
  if (lane == 0) sx2[row] = s;
  h4pack hi, lo;
  hi.h[0] = (_Float16)v.x; hi.h[1] = (_Float16)v.y;
  hi.h[2] = (_Float16)v.z; hi.h[3] = (_Float16)v.w;
  lo.h[0] = (_Float16)((v.x - (float)hi.h[0]) * 4096.0f);
  lo.h[1] = (_Float16)((v.y - (float)hi.h[1]) * 4096.0f);
  lo.h[2] = (_Float16)((v.z - (float)hi.h[2]) * 4096.0f);
  lo.h[3] = (_Float16)((v.w - (float)hi.h[3]) * 4096.0f);
  *(uint2*)&A[(size_t)row * 512 + 4 * lane] = hi.u2;
  *(uint2*)&A[(size_t)row * 512 + 256 + 4 * lane] = lo.u2;
}

// ---------------------------------------------------------------------------
// E -> B_cat[k][0:256]=B1=fp16(e*2^22), [256:512]=B1*2^-12, [512:768]=B3=
// fp16(e*2^22 - B1); also se2. (Bit-identical to the verified round-3 kernel.)
__global__ __launch_bounds__(256) void k_convB(const float* __restrict__ E,
                                               _Float16* __restrict__ Bc,
                                               float* __restrict__ se2) {
  int w = threadIdx.x >> 6, lane = threadIdx.x & 63;
  int row = blockIdx.x * 4 + w;
  float4 v = ((const float4*)(E + (size_t)row * D_DIM))[lane];
  float s = v.x * v.x + v.y * v.y + v.z * v.z + v.w * v.w;
#pragma unroll
  for (int off = 32; off > 0; off >>= 1) s += __shfl_xor(s, off, 64);
  if (lane == 0) se2[row] = s;
  const float S = 4194304.0f;       // 2^22
  const float SH = 0.000244140625f; // 2^-12
  float e0 = v.x * S, e1 = v.y * S, e2 = v.z * S, e3 = v.w * S;
  h4pack b1, b2, b3;
  b1.h[0] = (_Float16)e0; b1.h[1] = (_Float16)e1;
  b1.h[2] = (_Float16)e2; b1.h[3] = (_Float16)e3;
  b2.h[0] = (_Float16)((float)b1.h[0] * SH);
  b2.h[1] = (_Float16)((float)b1.h[1] * SH);
  b2.h[2] = (_Float16)((float)b1.h[2] * SH);
  b2.h[3] = (_Float16)((float)b1.h[3] * SH);
  b3.h[0] = (_Float16)(e0 - (float)b1.h[0]);
  b3.h[1] = (_Float16)(e1 - (float)b1.h[1]);
  b3.h[2] = (_Float16)(e2 - (float)b1.h[2]);
  b3.h[3] = (_Float16)(e3 - (float)b1.h[3]);
  *(uint2*)&Bc[(size_t)row * 768 + 4 * lane] = b1.u2;
  *(uint2*)&Bc[(size_t)row * 768 + 256 + 4 * lane] = b2.u2;
  *(uint2*)&Bc[(size_t)row * 768 + 512 + 4 * lane] = b3.u2;
}

// ---------------------------------------------------------------------------
// MFMA GEMM + argmin. Block = 256 thr (4 waves, 2x2 over 128x128 tile); each
// block covers 128 rows x 512 codes as 4 sequential col-tiles (ct), 24 K-steps
// each -> one 96-step software-pipelined K-loop per block. Grid 1024 = exactly
// 4 blocks/CU (LDS 33.3 KB). Ping-pong LDS: loads for step g+1 issued right
// after the barrier for step g, so the barrier's forced vmcnt(0) waits on
// loads that have had a full compute phase to land.
// dist math bit-identical to round 3: acc = dot*2^22 via 3-segment fp16 MFMA
// in the same order; d = (sx+se) - acc*2^-21.
// Argmin merge: packed u64 atomicMin of (fp32_bits(d)<<32)|k. d ~ +256 > 0 so
// bits order like uints; tie -> min k = global first-index (np.argmin).
__global__ __launch_bounds__(256, 4) void k_mfma(
    const _Float16* __restrict__ A, const _Float16* __restrict__ Bc,
    const float* __restrict__ se2, const float* __restrict__ sx2,
    unsigned long long* __restrict__ packed) {
  __shared__ _Float16 As[2][128 * 32];
  __shared__ _Float16 Bs[2][128 * 32];
  __shared__ float sxs[128];
  const int tid = threadIdx.x;
  const int w = tid >> 6, lane = tid & 63;
  const int rowblk = blockIdx.x & 255, cg = blockIdx.x >> 8;
  const int row0 = rowblk * 128, col00 = cg * 512;
  const int lr = lane >> 2, lc = lane & 3;  // staging row-in-slice / 16B col
  const int q = lane >> 4, c = lane & 15;   // MFMA lane decomposition
  const int wr = (w >> 1) * 64, wc = (w & 1) * 64;

  if (tid < 128) sxs[tid] = sx2[row0 + tid];

  const char* Abase = (const char*)A;
  const char* Bbase = (const char*)Bc;

  auto issue = [&](int ct_i, int ktl_i, int bsel) {
    // A col remap: steps 0..7 -> hi, 8..15 -> lo (pairs B2), 16..23 -> hi (B3)
    int a_off = (ktl_i < 8) ? ktl_i * 64
              : (ktl_i < 16) ? 512 + (ktl_i - 8) * 64 : (ktl_i - 16) * 64;
    int b_off = ktl_i * 64;
    int colb = col00 + ct_i * 128;
#pragma unroll
    for (int t = 0; t < 2; ++t) {
      int s = w * 2 + t;  // 8 slices of 16 rows, for A and for B
      const char* ga =
          Abase + (((size_t)(row0 + s * 16 + lr)) << 10) + a_off + lc * 16;
      const char* gb =
          Bbase + ((size_t)(colb + s * 16 + lr)) * 1536 + b_off + lc * 16;
      __builtin_amdgcn_global_load_lds(
          (const __attribute__((address_space(1))) unsigned int*)ga,
          (__attribute__((address_space(3))) unsigned int*)((char*)&As[bsel][0] +
                                                            s * 1024),
          16, 0, 0);
      __builtin_amdgcn_global_load_lds(
          (const __attribute__((address_space(1))) unsigned int*)gb,
          (__attribute__((address_space(3))) unsigned int*)((char*)&Bs[bsel][0] +
                                                            s * 1024),
          16, 0, 0);
    }
  };

  issue(0, 0, 0);  // prologue: first step's loads into buffer 0

  const float inv = 4.76837158203125e-07f;  // 2^-21, exact pow2
  for (int ct = 0; ct < 4; ++ct) {
    f32x4 acc[4][4];
#pragma unroll
    for (int i = 0; i < 4; i++)
#pragma unroll
      for (int j = 0; j < 4; j++) acc[i][j] = (f32x4){0.f, 0.f, 0.f, 0.f};

#pragma unroll 2
    for (int ktl = 0; ktl < 24; ++ktl) {
      __syncthreads();  // forced vmcnt(0) waits loads issued 1 full step ago
      int gidx = ct * 24 + ktl + 1;
      if (gidx < 96) issue(gidx / 24, gidx % 24, (ktl + 1) & 1);
      const int b = ktl & 1;
      f16x8 af[4], bf[4];
#pragma unroll
      for (int i = 0; i < 4; ++i) {
        af[i] = *(const f16x8*)&As[b][(wr + i * 16 + c) * 32 + q * 8];
        bf[i] = *(const f16x8*)&Bs[b][(wc + i * 16 + c) * 32 + q * 8];
      }
#pragma unroll
      for (int i = 0; i < 4; ++i)
#pragma unroll
        for (int j = 0; j < 4; ++j)
          acc[i][j] = __builtin_amdgcn_mfma_f32_16x16x32_f16(af[i], bf[j],
                                                             acc[i][j], 0, 0, 0);
    }

    // ---- ct epilogue (no barriers: registers + shuffles + atomics only) ----
    int colb = col00 + ct * 128;
    float se_j[4];
#pragma unroll
    for (int j = 0; j < 4; ++j) se_j[j] = se2[colb + wc + j * 16 + c];
#pragma unroll
    for (int i = 0; i < 4; ++i) {
#pragma unroll
      for (int r = 0; r < 4; ++r) {
        int lrow = wr + i * 16 + q * 4 + r;  // C layout: row = q*4 + reg
        float sx = sxs[lrow];
        float bs = 3.402823466e38f;
        int bk = 0;
#pragma unroll
        for (int j = 0; j < 4; ++j) {  // ascending j -> ascending code
          float t1 = sx + se_j[j];            // fp32 round 1 (matches ref)
          float d = t1 - acc[i][j][r] * inv;  // exact mul, fp32 round 2
          if (d < bs) { bs = d; bk = colb + wc + j * 16 + c; }
        }
#pragma unroll
        for (int off = 1; off < 16; off <<= 1) {  // reduce over c (q kept)
          float os = __shfl_xor(bs, off, 64);
          int ok = __shfl_xor(bk, off, 64);
          if (os < bs || (os == bs && ok < bk)) { bs = os; bk = ok; }
        }
        if (c == 0) {
          unsigned long long v =
              ((unsigned long long)__float_as_uint(bs) << 32) |
              (unsigned long long)(unsigned int)bk;
          atomicMin(&packed[row0 + lrow], v);
        }
      }
    }
  }
}

// ---------------------------------------------------------------------------
// Unpack winner per row, histogram, gather codebook rows (from ORIGINAL fp32
// E), STE output x + (q - x), per-wave double partials.
__global__ __launch_bounds__(256) void k_gather(
    const float* __restrict__ X, const float* __restrict__ E,
    const unsigned long long* __restrict__ packed, float* __restrict__ outq,
    float* __restrict__ out_ind, int* __restrict__ counts,
    double* __restrict__ msep, double* __restrict__ distp) {
  __shared__ int sk[16];
  __shared__ float sd[16];
  int tid = threadIdx.x;
  if (tid < 16) {
    int row = blockIdx.x * 16 + tid;
    unsigned long long v = packed[row];
    int k = (int)(v & 0xFFFFFFFFull);
    sk[tid] = k;
    sd[tid] = __uint_as_float((unsigned int)(v >> 32));
    out_ind[row] = (float)k;
    atomicAdd(&counts[k], 1);
  }
  __syncthreads();
  int wave = tid >> 6, lane = tid & 63;
  double msum = 0.0, dsum = 0.0;
#pragma unroll
  for (int rr = 0; rr < 4; rr++) {
    int li = wave * 4 + rr;
    int b = blockIdx.x * 16 + li;
    int ind = sk[li];
    float4 x4 = ((const float4*)(X + (size_t)b * D_DIM))[lane];
    float4 q4 = ((const float4*)(E + (size_t)ind * D_DIM))[lane];
    float d0 = q4.x - x4.x, d1 = q4.y - x4.y, d2 = q4.z - x4.z, d3 = q4.w - x4.w;
    float4 o;
    o.x = x4.x + d0; o.y = x4.y + d1; o.z = x4.z + d2; o.w = x4.w + d3;
    ((float4*)(outq + (size_t)b * D_DIM))[lane] = o;
    float v = d0 * d0 + d1 * d1 + d2 * d2 + d3 * d3;
#pragma unroll
    for (int off = 32; off > 0; off >>= 1) v += __shfl_xor(v, off, 64);
    if (lane == 0) { msum += (double)v; dsum += (double)sd[li]; }
  }
  if (lane == 0) {
    int wg = blockIdx.x * 4 + wave;
    msep[wg] = msum;
    distp[wg] = dsum;
  }
}

// ---------------------------------------------------------------------------
__global__ __launch_bounds__(256) void k_final(
    const int* __restrict__ counts, const double* __restrict__ msep,
    const double* __restrict__ distp, float* __restrict__ out) {
  __shared__ double red[256];
  int t = threadIdx.x;

  double m = 0.0;
  for (int i = t; i < 8192; i += 256) m += msep[i];
  red[t] = m;
  __syncthreads();
  for (int s = 128; s > 0; s >>= 1) {
    if (t < s) red[t] += red[t + s];
    __syncthreads();
  }
  if (t == 0) {
    double mse = red[0] / ((double)B_ROWS * (double)D_DIM);
    out[OUT_VQ] = (float)(mse * 1.25);  // 0.25*commit + embed
  }
  __syncthreads();

  double d = 0.0;
  for (int i = t; i < 8192; i += 256) d += distp[i];
  red[t] = d;
  __syncthreads();
  for (int s = 128; s > 0; s >>= 1) {
    if (t < s) red[t] += red[t + s];
    __syncthreads();
  }
  if (t == 0) out[OUT_CM] = (float)(red[0] / (double)B_ROWS);
  __syncthreads();

  double e = 0.0;
  for (int k = t; k < K_CODES; k += 256) {
    float p = (float)counts[k] * (1.0f / 32768.0f);
    e += (double)(p * logf(p + 1e-10f));
  }
  red[t] = e;
  __syncthreads();
  for (int s = 128; s > 0; s >>= 1) {
    if (t < s) red[t] += red[t + s];
    __syncthreads();
  }
  if (t == 0) out[OUT_ENT] = (float)(-red[0]);
}

// ---------------------------------------------------------------------------
extern "C" void kernel_launch(void* const* d_in, const int* in_sizes, int n_in,
                              void* d_out, int out_size, void* d_ws,
                              size_t ws_size, hipStream_t stream) {
  const float* X = (const float*)d_in[0];  // latents [32768,256]
  const float* E = (const float*)d_in[1];  // embedding [2048,256]
  float* out = (float*)d_out;
  char* ws = (char*)d_ws;
  float* se2 = (float*)(ws + WS_SE2);
  float* sx2 = (float*)(ws + WS_SX2);
  int* counts = (int*)(ws + WS_CNT);
  unsigned long long* packed = (unsigned long long*)(ws + WS_PACK);
  double* msep = (double*)(ws + WS_MSEP);
  double* distp = (double*)(ws + WS_DISTP);
  _Float16* Bcat = (_Float16*)(ws + WS_BCAT);
  _Float16* Acat = (_Float16*)d_out;  // Q region; k_gather overwrites later

  hipMemsetAsync(counts, 0, K_CODES * sizeof(int), stream);
  hipMemsetAsync(packed, 0xFF, B_ROWS * sizeof(unsigned long long), stream);
  k_convA<<<B_ROWS / 4, 256, 0, stream>>>(X, Acat, sx2);
  k_convB<<<K_CODES / 4, 256, 0, stream>>>(E, Bcat, se2);
  k_mfma<<<1024, 256, 0, stream>>>(Acat, Bcat, se2, sx2, packed);
  k_gather<<<B_ROWS / 16, 256, 0, stream>>>(X, E, packed, out + OUT_Q,
                                            out + OUT_IND, counts, msep, distp);
  k_final<<<1, 256, 0, stream>>>(counts, msep, distp, out);
}

// Round 5
// 272.094 us; speedup vs baseline: 3.0412x; 1.0181x over previous
//
#include <hip/hip_runtime.h>
#include <math.h>

#define B_ROWS 32768
#define D_DIM  256
#define K_CODES 2048

// d_out layout (float elements), reference return order:
// quantized_st [B,D], vq_loss, entropy, encoding_inds [B,1], cluster_metric
#define OUT_Q   0
#define OUT_VQ  8388608
#define OUT_ENT 8388609
#define OUT_IND 8388610
#define OUT_CM  8421378

// A_cat [32768][512] fp16 = 33.55 MB lives in the d_out Q region (exact fit);
// k_gather overwrites it with the real output afterwards.

// ws layout (bytes)
#define WS_SE2   0          // 2048 float
#define WS_SX2   8192       // 32768 float
#define WS_CNT   139264     // 2048 int   (zeroed in k_init)
#define WS_PACK  147456     // 32768 u64  (set to ~0 in k_init)
#define WS_MSEP  409600     // 8192 double
#define WS_DISTP 475136     // 8192 double
#define WS_BCAT  540672     // 2048 x 768 fp16 = 3 MB

typedef _Float16 f16x8 __attribute__((ext_vector_type(8)));
typedef float f32x4 __attribute__((ext_vector_type(4)));
typedef union { _Float16 h[4]; uint2 u2; } h4pack;

// ---------------------------------------------------------------------------
// Fused init: blocks [0,8192) convert X (fp16 hi/lo split + sx2) and set
// packed[row]=all-ones; blocks [8192,8704) convert E (3-segment split + se2)
// and zero the histogram. Replaces 2 kernels + 2 memsets (launch overhead).
__global__ __launch_bounds__(256) void k_init(
    const float* __restrict__ X, const float* __restrict__ E,
    _Float16* __restrict__ A, _Float16* __restrict__ Bc,
    float* __restrict__ sx2, float* __restrict__ se2,
    unsigned long long* __restrict__ packed, int* __restrict__ counts) {
  int w = threadIdx.x >> 6, lane = threadIdx.x & 63;
  if (blockIdx.x < 8192) {
    int row = blockIdx.x * 4 + w;
    float4 v = ((const float4*)(X + (size_t)row * D_DIM))[lane];
    float s = v.x * v.x + v.y * v.y + v.z * v.z + v.w * v.w;
#pragma unroll
    for (int off = 32; off > 0; off >>= 1) s += __shfl_xor(s, off, 64);
    if (lane == 0) { sx2[row] = s; packed[row] = ~0ull; }
    h4pack hi, lo;
    hi.h[0] = (_Float16)v.x; hi.h[1] = (_Float16)v.y;
    hi.h[2] = (_Float16)v.z; hi.h[3] = (_Float16)v.w;
    lo.h[0] = (_Float16)((v.x - (float)hi.h[0]) * 4096.0f);
    lo.h[1] = (_Float16)((v.y - (float)hi.h[1]) * 4096.0f);
    lo.h[2] = (_Float16)((v.z - (float)hi.h[2]) * 4096.0f);
    lo.h[3] = (_Float16)((v.w - (float)hi.h[3]) * 4096.0f);
    *(uint2*)&A[(size_t)row * 512 + 4 * lane] = hi.u2;
    *(uint2*)&A[(size_t)row * 512 + 256 + 4 * lane] = lo.u2;
  } else {
    int bb = blockIdx.x - 8192;
    int row = bb * 4 + w;
    if (threadIdx.x < 4) counts[bb * 4 + threadIdx.x] = 0;
    float4 v = ((const float4*)(E + (size_t)row * D_DIM))[lane];
    float s = v.x * v.x + v.y * v.y + v.z * v.z + v.w * v.w;
#pragma unroll
    for (int off = 32; off > 0; off >>= 1) s += __shfl_xor(s, off, 64);
    if (lane == 0) se2[row] = s;
    const float S = 4194304.0f;       // 2^22
    const float SH = 0.000244140625f; // 2^-12
    float e0 = v.x * S, e1 = v.y * S, e2 = v.z * S, e3 = v.w * S;
    h4pack b1, b2, b3;
    b1.h[0] = (_Float16)e0; b1.h[1] = (_Float16)e1;
    b1.h[2] = (_Float16)e2; b1.h[3] = (_Float16)e3;
    b2.h[0] = (_Float16)((float)b1.h[0] * SH);
    b2.h[1] = (_Float16)((float)b1.h[1] * SH);
    b2.h[2] = (_Float16)((float)b1.h[2] * SH);
    b2.h[3] = (_Float16)((float)b1.h[3] * SH);
    b3.h[0] = (_Float16)(e0 - (float)b1.h[0]);
    b3.h[1] = (_Float16)(e1 - (float)b1.h[1]);
    b3.h[2] = (_Float16)(e2 - (float)b1.h[2]);
    b3.h[3] = (_Float16)(e3 - (float)b1.h[3]);
    *(uint2*)&Bc[(size_t)row * 768 + 4 * lane] = b1.u2;
    *(uint2*)&Bc[(size_t)row * 768 + 256 + 4 * lane] = b2.u2;
    *(uint2*)&Bc[(size_t)row * 768 + 512 + 4 * lane] = b3.u2;
  }
}

// ---------------------------------------------------------------------------
// MFMA GEMM + argmin. Grid 2048: rowblk = blockIdx&255 (128 rows; same-rowblk
// blocks share XCD since XCD = blockIdx&7), cg = blockIdx>>8 (256 codes as 2
// col-tiles). 48-step ping-pong pipelined K-loop; LDS exactly 32 KB -> 5
// blocks/CU (20 waves) for phase decorrelation across blocks.
// dist math bit-identical to rounds 3/4: acc = dot*2^22 via 3-segment fp16
// MFMA, same order; d = (sx+se) - acc*2^-21. Merge via packed u64 atomicMin
// (d > 0 so fp32 bits order like uints; tie -> min k = np.argmin semantics).
__global__ __launch_bounds__(256, 4) void k_mfma(
    const _Float16* __restrict__ A, const _Float16* __restrict__ Bc,
    const float* __restrict__ se2, const float* __restrict__ sx2,
    unsigned long long* __restrict__ packed) {
  __shared__ _Float16 As[2][128 * 32];  // 16 KB
  __shared__ _Float16 Bs[2][128 * 32];  // 16 KB  -> total exactly 32768 B
  const int tid = threadIdx.x;
  const int w = tid >> 6, lane = tid & 63;
  const int rowblk = blockIdx.x & 255, cg = blockIdx.x >> 8;
  const int row0 = rowblk * 128, col00 = cg * 256;
  const int lr = lane >> 2, lc = lane & 3;  // staging row-in-slice / 16B col
  const int q = lane >> 4, c = lane & 15;   // MFMA lane decomposition
  const int wr = (w >> 1) * 64, wc = (w & 1) * 64;

  // per-lane epilogue rows: lrow = wr + i*16 + q*4 + r -> 4x float4 preload
  float4 srow[4];
#pragma unroll
  for (int i = 0; i < 4; ++i)
    srow[i] = *(const float4*)&sx2[row0 + wr + i * 16 + q * 4];

  const char* Abase = (const char*)A;
  const char* Bbase = (const char*)Bc;

  auto issue = [&](int ct_i, int ktl_i, int bsel) {
    // A col remap: steps 0..7 -> hi, 8..15 -> lo (pairs B2), 16..23 -> hi (B3)
    int a_off = (ktl_i < 8) ? ktl_i * 64
              : (ktl_i < 16) ? 512 + (ktl_i - 8) * 64 : (ktl_i - 16) * 64;
    int b_off = ktl_i * 64;
    int colb = col00 + ct_i * 128;
#pragma unroll
    for (int t = 0; t < 2; ++t) {
      int s = w * 2 + t;  // 8 slices of 16 rows, for A and for B
      const char* ga =
          Abase + (((size_t)(row0 + s * 16 + lr)) << 10) + a_off + lc * 16;
      const char* gb =
          Bbase + ((size_t)(colb + s * 16 + lr)) * 1536 + b_off + lc * 16;
      __builtin_amdgcn_global_load_lds(
          (const __attribute__((address_space(1))) unsigned int*)ga,
          (__attribute__((address_space(3))) unsigned int*)((char*)&As[bsel][0] +
                                                            s * 1024),
          16, 0, 0);
      __builtin_amdgcn_global_load_lds(
          (const __attribute__((address_space(1))) unsigned int*)gb,
          (__attribute__((address_space(3))) unsigned int*)((char*)&Bs[bsel][0] +
                                                            s * 1024),
          16, 0, 0);
    }
  };

  issue(0, 0, 0);  // prologue

  const float inv = 4.76837158203125e-07f;  // 2^-21, exact pow2
  for (int ct = 0; ct < 2; ++ct) {
    f32x4 acc[4][4];
#pragma unroll
    for (int i = 0; i < 4; i++)
#pragma unroll
      for (int j = 0; j < 4; j++) acc[i][j] = (f32x4){0.f, 0.f, 0.f, 0.f};

#pragma unroll 2
    for (int ktl = 0; ktl < 24; ++ktl) {
      __syncthreads();  // forced vmcnt(0) waits loads issued 1 full step ago
      int gidx = ct * 24 + ktl + 1;
      if (gidx < 48) issue(gidx / 24, gidx % 24, (ktl + 1) & 1);
      const int b = ktl & 1;
      f16x8 af[4], bf[4];
#pragma unroll
      for (int i = 0; i < 4; ++i) {
        af[i] = *(const f16x8*)&As[b][(wr + i * 16 + c) * 32 + q * 8];
        bf[i] = *(const f16x8*)&Bs[b][(wc + i * 16 + c) * 32 + q * 8];
      }
#pragma unroll
      for (int i = 0; i < 4; ++i)
#pragma unroll
        for (int j = 0; j < 4; ++j)
          acc[i][j] = __builtin_amdgcn_mfma_f32_16x16x32_f16(af[i], bf[j],
                                                             acc[i][j], 0, 0, 0);
    }

    // ---- ct epilogue (no barriers: registers + shuffles + atomics only) ----
    int colb = col00 + ct * 128;
    float se_j[4];
#pragma unroll
    for (int j = 0; j < 4; ++j) se_j[j] = se2[colb + wc + j * 16 + c];
#pragma unroll
    for (int i = 0; i < 4; ++i) {
#pragma unroll
      for (int r = 0; r < 4; ++r) {
        int lrow = wr + i * 16 + q * 4 + r;  // C layout: row = q*4 + reg
        float sx = ((const float*)&srow[i])[r];
        float bs = 3.402823466e38f;
        int bk = 0;
#pragma unroll
        for (int j = 0; j < 4; ++j) {  // ascending j -> ascending code
          float t1 = sx + se_j[j];            // fp32 round 1 (matches ref)
          float d = t1 - acc[i][j][r] * inv;  // exact mul, fp32 round 2
          if (d < bs) { bs = d; bk = colb + wc + j * 16 + c; }
        }
#pragma unroll
        for (int off = 1; off < 16; off <<= 1) {  // reduce over c (q kept)
          float os = __shfl_xor(bs, off, 64);
          int ok = __shfl_xor(bk, off, 64);
          if (os < bs || (os == bs && ok < bk)) { bs = os; bk = ok; }
        }
        if (c == 0) {
          unsigned long long v =
              ((unsigned long long)__float_as_uint(bs) << 32) |
              (unsigned long long)(unsigned int)bk;
          atomicMin(&packed[row0 + lrow], v);
        }
      }
    }
  }
}

// ---------------------------------------------------------------------------
// Unpack winner per row, histogram, gather codebook rows (from ORIGINAL fp32
// E), STE output x + (q - x), per-wave double partials.
__global__ __launch_bounds__(256) void k_gather(
    const float* __restrict__ X, const float* __restrict__ E,
    const unsigned long long* __restrict__ packed, float* __restrict__ outq,
    float* __restrict__ out_ind, int* __restrict__ counts,
    double* __restrict__ msep, double* __restrict__ distp) {
  __shared__ int sk[16];
  __shared__ float sd[16];
  int tid = threadIdx.x;
  if (tid < 16) {
    int row = blockIdx.x * 16 + tid;
    unsigned long long v = packed[row];
    int k = (int)(v & 0xFFFFFFFFull);
    sk[tid] = k;
    sd[tid] = __uint_as_float((unsigned int)(v >> 32));
    out_ind[row] = (float)k;
    atomicAdd(&counts[k], 1);
  }
  __syncthreads();
  int wave = tid >> 6, lane = tid & 63;
  double msum = 0.0, dsum = 0.0;
#pragma unroll
  for (int rr = 0; rr < 4; rr++) {
    int li = wave * 4 + rr;
    int b = blockIdx.x * 16 + li;
    int ind = sk[li];
    float4 x4 = ((const float4*)(X + (size_t)b * D_DIM))[lane];
    float4 q4 = ((const float4*)(E + (size_t)ind * D_DIM))[lane];
    float d0 = q4.x - x4.x, d1 = q4.y - x4.y, d2 = q4.z - x4.z, d3 = q4.w - x4.w;
    float4 o;
    o.x = x4.x + d0; o.y = x4.y + d1; o.z = x4.z + d2; o.w = x4.w + d3;
    ((float4*)(outq + (size_t)b * D_DIM))[lane] = o;
    float v = d0 * d0 + d1 * d1 + d2 * d2 + d3 * d3;
#pragma unroll
    for (int off = 32; off > 0; off >>= 1) v += __shfl_xor(v, off, 64);
    if (lane == 0) { msum += (double)v; dsum += (double)sd[li]; }
  }
  if (lane == 0) {
    int wg = blockIdx.x * 4 + wave;
    msep[wg] = msum;
    distp[wg] = dsum;
  }
}

// ---------------------------------------------------------------------------
__global__ __launch_bounds__(256) void k_final(
    const int* __restrict__ counts, const double* __restrict__ msep,
    const double* __restrict__ distp, float* __restrict__ out) {
  __shared__ double red[256];
  int t = threadIdx.x;

  double m = 0.0;
  for (int i = t; i < 8192; i += 256) m += msep[i];
  red[t] = m;
  __syncthreads();
  for (int s = 128; s > 0; s >>= 1) {
    if (t < s) red[t] += red[t + s];
    __syncthreads();
  }
  if (t == 0) {
    double mse = red[0] / ((double)B_ROWS * (double)D_DIM);
    out[OUT_VQ] = (float)(mse * 1.25);  // 0.25*commit + embed
  }
  __syncthreads();

  double d = 0.0;
  for (int i = t; i < 8192; i += 256) d += distp[i];
  red[t] = d;
  __syncthreads();
  for (int s = 128; s > 0; s >>= 1) {
    if (t < s) red[t] += red[t + s];
    __syncthreads();
  }
  if (t == 0) out[OUT_CM] = (float)(red[0] / (double)B_ROWS);
  __syncthreads();

  double e = 0.0;
  for (int k = t; k < K_CODES; k += 256) {
    float p = (float)counts[k] * (1.0f / 32768.0f);
    e += (double)(p * logf(p + 1e-10f));
  }
  red[t] = e;
  __syncthreads();
  for (int s = 128; s > 0; s >>= 1) {
    if (t < s) red[t] += red[t + s];
    __syncthreads();
  }
  if (t == 0) out[OUT_ENT] = (float)(-red[0]);
}

// ---------------------------------------------------------------------------
extern "C" void kernel_launch(void* const* d_in, const int* in_sizes, int n_in,
                              void* d_out, int out_size, void* d_ws,
                              size_t ws_size, hipStream_t stream) {
  const float* X = (const float*)d_in[0];  // latents [32768,256]
  const float* E = (const float*)d_in[1];  // embedding [2048,256]
  float* out = (float*)d_out;
  char* ws = (char*)d_ws;
  float* se2 = (float*)(ws + WS_SE2);
  float* sx2 = (float*)(ws + WS_SX2);
  int* counts = (int*)(ws + WS_CNT);
  unsigned long long* packed = (unsigned long long*)(ws + WS_PACK);
  double* msep = (double*)(ws + WS_MSEP);
  double* distp = (double*)(ws + WS_DISTP);
  _Float16* Bcat = (_Float16*)(ws + WS_BCAT);
  _Float16* Acat = (_Float16*)d_out;  // Q region; k_gather overwrites later

  k_init<<<8704, 256, 0, stream>>>(X, E, Acat, Bcat, sx2, se2, packed, counts);
  k_mfma<<<2048, 256, 0, stream>>>(Acat, Bcat, se2, sx2, packed);
  k_gather<<<B_ROWS / 16, 256, 0, stream>>>(X, E, packed, out + OUT_Q,
                                            out + OUT_IND, counts, msep, distp);
  k_final<<<1, 256, 0, stream>>>(counts, msep, distp, out);
}